// Round 8
// baseline (68.604 us; speedup 1.0000x reference)
//
#include <hip/hip_runtime.h>
#include <stdint.h>

#define NN 2048
#define TPB 256        // 4 independent waves per block; each wave owns ONE row
#define WPB 4          // waves per block
#define KNB 16
#define CAP 128        // candidate capacity per wave
#define CAPPAD (CAP + 8)

static constexpr unsigned long long EXCL = ~0ull;
// Threshold 0.046875f (= 3/64): candidate iff dist < T0 (bits < 0x3D400000),
// twc != 0, j != i. Over 2048 entries: ~96 pass dist, ~48 also pass twc.
// c ~ Bin(1024, 3/64): mean 48, sigma 6.8; P(c<16) ~ 7e-7, P(c>128) ~ 0.
// Both tails -> exact wave-local fallback (always correct).
static constexpr float T0F = 0.046875f;
static constexpr unsigned long long T0KEY = ((unsigned long long)0x3D400000u) << 11;

// Wave-local LDS sync: drain this wave's own LDS ops. No s_barrier anywhere —
// waves are fully independent; "memory" stops compiler reordering around it.
#define WAVE_LDS_SYNC() asm volatile("s_waitcnt lgkmcnt(0)" ::: "memory")

__global__ __launch_bounds__(TPB, 8) void encoder_mask_kernel(
    const float* __restrict__ D,      // [B,N,N]
    const int*   __restrict__ TWC,    // [B,N,N]
    const int*   __restrict__ depot,  // [B,N]
    float*       __restrict__ out)    // [B,N,N]
{
    const int t    = threadIdx.x;
    const int w    = t >> 6;               // wave id 0..3
    const int lane = t & 63;
    const int row  = blockIdx.x * WPB + w; // global row = b*N + i
    const int b    = row >> 11;
    const int i    = row & (NN - 1);

    const int* deprow = depot + b * NN;
    float*     orow   = out + (size_t)row * NN;
    const int  depot_i = deprow[i];        // wave-uniform

    // Fast path (wave-uniform branch; no barriers in this kernel -> safe):
    // depot[b,i]==1 -> whole row ones; wave retires immediately.
    if (depot_i != 0) {
        const float4 ones = make_float4(1.f, 1.f, 1.f, 1.f);
        #pragma unroll
        for (int k = 0; k < 8; ++k)
            reinterpret_cast<float4*>(orow)[lane + 64 * k] = ones;
        return;
    }

    const float* drow = D   + (size_t)row * NN;
    const int*   trow = TWC + (size_t)row * NN;

    // ---- Issue ALL D loads upfront: 8x float4 = one HBM round-trip (max MLP).
    float4 dv[8];
    #pragma unroll
    for (int k = 0; k < 8; ++k)
        dv[k] = reinterpret_cast<const float4*>(drow)[lane + 64 * k];

    // Per-wave private LDS partitions (no cross-wave sharing).
    __shared__ unsigned int       selq[WPB][512];     // byte-map as u32[512]
    __shared__ unsigned long long cand[WPB][CAPPAD];
    __shared__ int                cnt[WPB];

    // Init under load latency: selq <- 0 (+diag byte), cand <- EXCL, cnt <- 0.
    if (lane == 0) cnt[w] = 0;
    cand[w][lane]      = EXCL;
    cand[w][lane + 64] = EXCL;
    if (lane < CAPPAD - 128) cand[w][128 + lane] = EXCL;
    #pragma unroll
    for (int k = 0; k < 8; ++k) selq[w][lane + 64 * k] = 0u;
    if (lane == 0)
        reinterpret_cast<unsigned char*>(&selq[w][0])[i] = 1;   // diagonal
    WAVE_LDS_SYNC();

    // ---- Dist-first filter: only dist-passing elements read TWC (scalar). ----
    // Keys: (dist_bits << 11) | j, unique (index bits) -> reproduces lax.top_k's
    // lowest-index tie-break exactly. Candidate iff dist<T0 & twc!=0 & j!=i.
    #pragma unroll
    for (int k = 0; k < 8; ++k) {
        const int jb = 4 * (lane + 64 * k);
        const float dd[4] = {dv[k].x, dv[k].y, dv[k].z, dv[k].w};
        #pragma unroll
        for (int q = 0; q < 4; ++q) {
            const int j = jb + q;
            if ((dd[q] < T0F) & (j != i)) {           // rare: ~1.5 per lane total
                if (trow[j] != 0) {                   // conditional scalar TWC read
                    const unsigned long long kk =
                        ((((unsigned long long)__float_as_uint(dd[q])) << 11) |
                         (unsigned long long)(unsigned)j);
                    const int p = atomicAdd(&cnt[w], 1);
                    if (p < CAP) cand[w][p] = kk;
                }
            }
        }
    }
    WAVE_LDS_SYNC();

    const int c = cnt[w];

    if (c >= KNB && c <= CAP) {
        // ---- Rank selection: lane owns cand[lane], cand[lane+64]. c >= 16 keys
        // below T0 -> global top-16 all in cand[]. Uniform-address 8-wide LDS
        // reads (broadcast, conflict-free); both ranks in one pass.
        const unsigned long long k0 = cand[w][lane];
        const unsigned long long k1 = cand[w][lane + 64];
        int r0 = 0, r1 = 0;
        const int cround = (c + 7) & ~7;
        #pragma unroll 1
        for (int q = 0; q < cround; q += 8) {
            const ulonglong2 a0 = *reinterpret_cast<const ulonglong2*>(&cand[w][q]);
            const ulonglong2 a1 = *reinterpret_cast<const ulonglong2*>(&cand[w][q + 2]);
            const ulonglong2 a2 = *reinterpret_cast<const ulonglong2*>(&cand[w][q + 4]);
            const ulonglong2 a3 = *reinterpret_cast<const ulonglong2*>(&cand[w][q + 6]);
            r0 += (a0.x < k0) + (a0.y < k0) + (a1.x < k0) + (a1.y < k0)
                + (a2.x < k0) + (a2.y < k0) + (a3.x < k0) + (a3.y < k0);
            r1 += (a0.x < k1) + (a0.y < k1) + (a1.x < k1) + (a1.y < k1)
                + (a2.x < k1) + (a2.y < k1) + (a3.x < k1) + (a3.y < k1);
        }
        unsigned char* selb = reinterpret_cast<unsigned char*>(&selq[w][0]);
        if (lane      < c && r0 < KNB) selb[(int)(k0 & 2047u)] = 1;
        if (lane + 64 < c && r1 < KNB) selb[(int)(k1 & 2047u)] = 1;
    } else {
        // ---- Exact fallback (P ~ 7e-7/row): 16 rounds of wave-min extraction,
        // re-reading D/TWC from global (L2-hot). Winner keys strictly increase.
        unsigned long long glast = 0ull;
        #pragma unroll 1
        for (int it = 0; it < KNB; ++it) {
            unsigned long long lmin = EXCL;
            #pragma unroll 1
            for (int k = 0; k < 8; ++k) {
                const int idx = lane + 64 * k;
                const float4 d4 = reinterpret_cast<const float4*>(drow)[idx];
                const int4   c4 = reinterpret_cast<const int4*>(trow)[idx];
                const int jb = 4 * idx;
                const float dd[4] = {d4.x, d4.y, d4.z, d4.w};
                const int   cc[4] = {c4.x, c4.y, c4.z, c4.w};
                #pragma unroll
                for (int q = 0; q < 4; ++q) {
                    const int j = jb + q;
                    const bool excl = (cc[q] == 0) | (j == i);
                    const unsigned long long kq = excl ? EXCL
                        : ((((unsigned long long)__float_as_uint(dd[q])) << 11) |
                           (unsigned long long)(unsigned)j);
                    const bool ok = (it == 0) | (kq > glast);
                    if (ok && kq < lmin) lmin = kq;
                }
            }
            #pragma unroll
            for (int off = 32; off >= 1; off >>= 1) {
                const unsigned long long o = __shfl_xor(lmin, off);
                lmin = (o < lmin) ? o : lmin;
            }
            if (lmin == EXCL) break;                 // < 16 unblocked entries
            if (lane == 0)
                reinterpret_cast<unsigned char*>(&selq[w][0])[(int)(lmin & 2047u)] = 1;
            glast = lmin;
        }
    }
    WAVE_LDS_SYNC();

    // ---- Tail: out = selq(sel|diag) | depot_j. Depot row is 8 KB, L2-hot. ----
    #pragma unroll
    for (int k = 0; k < 8; ++k) {
        const int idx = lane + 64 * k;
        const int4 dp = reinterpret_cast<const int4*>(deprow)[idx];
        const unsigned int s = selq[w][idx];
        float4 o;
        o.x = ((s & 0x000000ffu) | (dp.x != 0)) ? 1.f : 0.f;
        o.y = ((s & 0x0000ff00u) | (dp.y != 0)) ? 1.f : 0.f;
        o.z = ((s & 0x00ff0000u) | (dp.z != 0)) ? 1.f : 0.f;
        o.w = ((s & 0xff000000u) | (dp.w != 0)) ? 1.f : 0.f;
        reinterpret_cast<float4*>(orow)[idx] = o;
    }
}

extern "C" void kernel_launch(void* const* d_in, const int* in_sizes, int n_in,
                              void* d_out, int out_size, void* d_ws, size_t ws_size,
                              hipStream_t stream) {
    const float* D     = (const float*)d_in[0];   // distance_matrix [B,N,N]
    // d_in[1] = max_dist — provably irrelevant (blocked entries never survive)
    const int*   TWC   = (const int*)d_in[2];     // time_window_compatibility [B,N,N]
    const int*   depot = (const int*)d_in[3];     // depot [B,N]
    // d_in[4] = num_neighbors_encoder == 16 (compile-time KNB)

    float* outp = (float*)d_out;
    const int rows = in_sizes[3];                 // B*N = 16384

    encoder_mask_kernel<<<rows / WPB, TPB, 0, stream>>>(D, TWC, depot, outp);
}

// Round 9
// 52.613 us; speedup vs baseline: 1.3039x; 1.3039x over previous
//
#include <hip/hip_runtime.h>
#include <stdint.h>

#define NN 2048
#define TPB 256
#define EPT 8          // NN / TPB
#define KNB 16
#define CAP 128        // candidate capacity (<= TPB so one thread per candidate)
#define CAPPAD (CAP + 8)

static constexpr unsigned long long EXCL = ~0ull;
// Threshold 0.046875f (= 3/64): dist_bits < 0x3D400000 -> candidate.
// ~1024 unblocked entries/row, c ~ Bin(1024, 3/64): mean 48, sigma 6.8;
// P(c<16) ~ 7e-7, P(c>128) ~ 0. Both tails -> exact fallback (always correct).
static constexpr unsigned long long T0KEY = ((unsigned long long)0x3D400000u) << 11;

__global__ __launch_bounds__(TPB) void encoder_mask_kernel(
    const float* __restrict__ D,      // [B,N,N]
    const int*   __restrict__ TWC,    // [B,N,N]
    const int*   __restrict__ depot,  // [B,N]
    float*       __restrict__ out)    // [B,N,N]
{
    const int row = blockIdx.x;       // b*N + i
    const int b   = row >> 11;
    const int i   = row & (NN - 1);
    const int t   = threadIdx.x;
    const int j0  = t * EPT;

    float*     orow   = out + (size_t)row * NN;
    const int* deprow = depot + b * NN;

    // depot loads first (64 KB total -> L2/L3-hot, returns fast).
    const int4 p0 = reinterpret_cast<const int4*>(deprow + j0)[0];
    const int4 p1 = reinterpret_cast<const int4*>(deprow + j0)[1];
    const int  depot_i = deprow[i];   // block-uniform -> branch safe w.r.t. barriers

    // Fast path: depot[b,i]==1 -> entire row ones; no D/TWC reads at all.
    if (depot_i != 0) {
        const float4 ones = make_float4(1.f, 1.f, 1.f, 1.f);
        float4* o4 = reinterpret_cast<float4*>(orow + j0);
        o4[0] = ones;
        o4[1] = ones;
        return;
    }

    const float* drow = D   + (size_t)row * NN;
    const int*   trow = TWC + (size_t)row * NN;

    // Heavy loads in flight; LDS init hides under their latency.
    const float4 d0 = reinterpret_cast<const float4*>(drow + j0)[0];
    const float4 d1 = reinterpret_cast<const float4*>(drow + j0)[1];
    const int4   c0 = reinterpret_cast<const int4*>(trow + j0)[0];
    const int4   c1 = reinterpret_cast<const int4*>(trow + j0)[1];

    __shared__ unsigned long long cand[CAPPAD];
    __shared__ unsigned long long wpart[2][TPB / 64];
    __shared__ int cnt;

    if (t < CAPPAD) cand[t] = EXCL;   // pad so rank loop can read 8-wide
    if (t == 0) cnt = 0;
    __syncthreads();                  // barrier#0: LDS init visible

    // ---- BULK STORE, decoupled from selection ------------------------------
    // Selection flips at most 16 of 2048 elements to 1. Store depot_j|diag for
    // the whole row NOW (depot regs are ready); the <=16 winners are overwritten
    // with 1.0f after rank. This puts the 8 KB write (half of all traffic) in
    // flight ~2k cycles earlier, overlapping the filter+rank phases.
    {
        const int dpv[EPT] = {p0.x, p0.y, p0.z, p0.w, p1.x, p1.y, p1.z, p1.w};
        float ov[EPT];
        #pragma unroll
        for (int k = 0; k < EPT; ++k) {
            const int j = j0 + k;
            ov[k] = ((dpv[k] != 0) | (j == i)) ? 1.0f : 0.0f;
        }
        float4* o4 = reinterpret_cast<float4*>(orow + j0);
        o4[0] = make_float4(ov[0], ov[1], ov[2], ov[3]);
        o4[1] = make_float4(ov[4], ov[5], ov[6], ov[7]);
    }

    // ---- Keys + filter ------------------------------------------------------
    // Keys: (dist_bits << 11) | j ; excluded -> EXCL. dist in [0,1) -> key < 2^41.
    // Unique index bits reproduce lax.top_k's lowest-index tie-break exactly.
    const float dv[EPT] = {d0.x, d0.y, d0.z, d0.w, d1.x, d1.y, d1.z, d1.w};
    const int   cv[EPT] = {c0.x, c0.y, c0.z, c0.w, c1.x, c1.y, c1.z, c1.w};

    unsigned long long key[EPT];
    #pragma unroll
    for (int k = 0; k < EPT; ++k) {
        const int j = j0 + k;
        const bool excl = (cv[k] == 0) | (j == i);
        key[k] = excl ? EXCL
                      : ((((unsigned long long)__float_as_uint(dv[k])) << 11) |
                         (unsigned long long)(unsigned)j);
    }

    // Count (static) -> one atomic -> place (static unroll; runtime LDS index is
    // fine, runtime-indexed PRIVATE arrays are not — R4 lesson).
    int nloc = 0;
    #pragma unroll
    for (int k = 0; k < EPT; ++k) nloc += (key[k] < T0KEY) ? 1 : 0;
    if (nloc > 0) {
        int idx = atomicAdd(&cnt, nloc);
        #pragma unroll
        for (int k = 0; k < EPT; ++k) {
            if (key[k] < T0KEY) {
                if (idx < CAP) cand[idx] = key[k];
                ++idx;
            }
        }
    }

    // Bulk stores must be globally complete before any winner overwrite:
    // drain own stores, then rendezvous (all waves' stores done at the barrier).
    asm volatile("s_waitcnt vmcnt(0)" ::: "memory");
    __syncthreads();                  // B1: cand/cnt ready AND bulk stores done

    const int c = cnt;

    if (c >= KNB && c <= CAP) {
        // Rank selection: thread t owns cand[t]; uniform-address 8-wide LDS reads
        // (broadcast, conflict-free). rank < 16 <=> exact top-16. Winners write
        // their single output element directly.
        if (t < c) {
            const unsigned long long mykey = cand[t];
            int rank = 0;
            const int cround = (c + 7) & ~7;
            #pragma unroll 1
            for (int q = 0; q < cround; q += 8) {
                const ulonglong2 a0 = *reinterpret_cast<const ulonglong2*>(&cand[q]);
                const ulonglong2 a1 = *reinterpret_cast<const ulonglong2*>(&cand[q + 2]);
                const ulonglong2 a2 = *reinterpret_cast<const ulonglong2*>(&cand[q + 4]);
                const ulonglong2 a3 = *reinterpret_cast<const ulonglong2*>(&cand[q + 6]);
                rank += (a0.x < mykey) ? 1 : 0;
                rank += (a0.y < mykey) ? 1 : 0;
                rank += (a1.x < mykey) ? 1 : 0;
                rank += (a1.y < mykey) ? 1 : 0;
                rank += (a2.x < mykey) ? 1 : 0;
                rank += (a2.y < mykey) ? 1 : 0;
                rank += (a3.x < mykey) ? 1 : 0;
                rank += (a3.y < mykey) ? 1 : 0;
            }
            if (rank < KNB) {
                orow[(int)(mykey & 2047u)] = 1.0f;   // scatter overwrite, <=16/row
            }
        }
    } else {
        // Exact fallback (P ~ 7e-7/row): iterative global-min extraction from
        // the register keys; winner stored directly each round.
        const int wave = t >> 6;
        const int lane = t & 63;
        unsigned long long lmin = key[0];
        #pragma unroll
        for (int k = 1; k < EPT; ++k) lmin = (key[k] < lmin) ? key[k] : lmin;

        #pragma unroll 1
        for (int it = 0; it < KNB; ++it) {
            unsigned long long w = lmin;
            #pragma unroll
            for (int off = 32; off >= 1; off >>= 1) {
                const unsigned long long o = __shfl_xor(w, off);
                w = (o < w) ? o : w;
            }
            const int pp = it & 1;
            if (lane == 0) wpart[pp][wave] = w;
            __syncthreads();
            unsigned long long gm = wpart[pp][0];
            {
                const unsigned long long g1 = wpart[pp][1];
                const unsigned long long g2 = wpart[pp][2];
                const unsigned long long g3 = wpart[pp][3];
                gm = (g1 < gm) ? g1 : gm;
                gm = (g2 < gm) ? g2 : gm;
                gm = (g3 < gm) ? g3 : gm;
            }
            if (gm == EXCL) break;
            if (t == 0) orow[(int)(gm & 2047u)] = 1.0f;
            if (lmin == gm) {
                unsigned long long nm = EXCL;
                #pragma unroll
                for (int k = 0; k < EPT; ++k) {
                    if (key[k] == gm) key[k] = EXCL;
                    nm = (key[k] < nm) ? key[k] : nm;
                }
                lmin = nm;
            }
        }
    }
    // No tail: bulk row already stored; winners already overwritten.
}

extern "C" void kernel_launch(void* const* d_in, const int* in_sizes, int n_in,
                              void* d_out, int out_size, void* d_ws, size_t ws_size,
                              hipStream_t stream) {
    const float* D     = (const float*)d_in[0];   // distance_matrix [B,N,N]
    // d_in[1] = max_dist — provably irrelevant (blocked entries never survive)
    const int*   TWC   = (const int*)d_in[2];     // time_window_compatibility [B,N,N]
    const int*   depot = (const int*)d_in[3];     // depot [B,N]
    // d_in[4] = num_neighbors_encoder == 16 (compile-time KNB)

    float* outp = (float*)d_out;
    const int rows = in_sizes[3];                 // B*N = 16384

    encoder_mask_kernel<<<rows, TPB, 0, stream>>>(D, TWC, depot, outp);
}